// Round 3
// baseline (49.179 us; speedup 1.0000x reference)
//
#include <hip/hip_runtime.h>
#include <math.h>

#define NCITY 384
#define BATCH 4
#define DIM   128
#define HID   256
#define M_TOT (BATCH * NCITY)   // 1536 rows (cities across batches)

// ---------------------------------------------------------------------------
// K1: emb = relu(cities@We1 + be1) @ We2 + be2        [1536 x 128]
// GEMM M=1536 N=128 K=256. Tile 16 cities x 64 dims; grid (2, 96).
// h1 (A-operand) computed in-register from cities+We1 (2 FMA + relu), staged
// to LDS padded-260. We2 chunked [64k x 64d] into LDS padded-68.
// Thread: tm=tid>>4 -> city, tn=tid&15 -> col-quad. 4 outputs/thread.
// ---------------------------------------------------------------------------
__global__ __launch_bounds__(256) void emb_kernel(
    const float* __restrict__ cities,
    const float* __restrict__ We1, const float* __restrict__ be1,
    const float* __restrict__ We2, const float* __restrict__ be2,
    float* __restrict__ emb)
{
    __shared__ float As[16 * 260];   // h1 tile, pad 256+4
    __shared__ float Bs[64 * 68];    // We2 chunk, pad 64+4
    __shared__ float cs[32];

    const int tid = threadIdx.x;
    const int c0  = blockIdx.y * 16;
    const int d0  = blockIdx.x * 64;

    if (tid < 32) cs[tid] = cities[c0 * 2 + tid];
    const float w0 = We1[tid], w1 = We1[HID + tid], b1 = be1[tid];
    __syncthreads();

    // h1[c][k=tid] — bank-spread writes (4c + tid) % 32
    #pragma unroll
    for (int c = 0; c < 16; ++c) {
        const float2 xy = *(const float2*)&cs[2 * c];
        As[c * 260 + tid] = fmaxf(fmaf(xy.x, w0, fmaf(xy.y, w1, b1)), 0.f);
    }

    const int tm = tid >> 4, tn = tid & 15;
    float4 acc = {0.f, 0.f, 0.f, 0.f};

    for (int cc = 0; cc < 4; ++cc) {
        __syncthreads();
        {   // stage We2[cc*64 .. +64)[d0 .. d0+64)
            const int u = tid & 15, kk = tid >> 4;
            #pragma unroll
            for (int m = 0; m < 4; ++m) {
                const int k = kk + m * 16;
                *(float4*)&Bs[k * 68 + u * 4] =
                    *(const float4*)&We2[(cc * 64 + k) * DIM + d0 + u * 4];
            }
        }
        __syncthreads();
        #pragma unroll 4
        for (int k4 = 0; k4 < 16; ++k4) {
            const float4 a4 = *(const float4*)&As[tm * 260 + cc * 64 + k4 * 4];
            #pragma unroll
            for (int m = 0; m < 4; ++m) {
                const float4 b4 = *(const float4*)&Bs[(k4 * 4 + m) * 68 + tn * 4];
                const float a = (m == 0) ? a4.x : (m == 1) ? a4.y : (m == 2) ? a4.z : a4.w;
                acc.x = fmaf(a, b4.x, acc.x);
                acc.y = fmaf(a, b4.y, acc.y);
                acc.z = fmaf(a, b4.z, acc.z);
                acc.w = fmaf(a, b4.w, acc.w);
            }
        }
    }

    const float4 be4 = *(const float4*)&be2[d0 + tn * 4];
    acc.x += be4.x; acc.y += be4.y; acc.z += be4.z; acc.w += be4.w;
    *(float4*)&emb[(c0 + tm) * DIM + d0 + tn * 4] = acc;
}

// ---------------------------------------------------------------------------
// K2: [att_h | Ai | Aj] = emb @ [Wa1 | Wd1[:128] | Wd1[128:]]   M=1536 N=768 K=128
// Tile 64 x 64, 4x4 per thread; grid (12, 24). col-blocks 0-3: attention
// (relu+*wa2, 16-lane shfl reduce -> per-colblock partial score, no atomics);
// 4-7: Ai (+bd1); 8-11: Aj.
// ---------------------------------------------------------------------------
__global__ __launch_bounds__(256) void heads_kernel(
    const float* __restrict__ emb,
    const float* __restrict__ Wa1, const float* __restrict__ ba1,
    const float* __restrict__ wa2,
    const float* __restrict__ Wd1, const float* __restrict__ bd1,
    float* __restrict__ score_part, float* __restrict__ Ai, float* __restrict__ Aj)
{
    __shared__ float As[64 * 132];   // emb tile, pad 128+4
    __shared__ float Bs[64 * 68];    // weight chunk, pad 64+4

    const int tid = threadIdx.x;
    const int r0  = blockIdx.y * 64;
    const int bn  = blockIdx.x;
    const int seg = bn >> 2;                 // 0=att 1=Ai 2=Aj
    const int cb  = (bn & 3) * 64;
    const float* Bsrc = (seg == 0) ? Wa1 : (seg == 1 ? Wd1 : Wd1 + DIM * HID);

    {   // stage A: emb[r0..r0+64)[0..128)
        const int c = tid >> 2, u = tid & 3;
        #pragma unroll
        for (int v = 0; v < 8; ++v)
            *(float4*)&As[c * 132 + u * 32 + v * 4] =
                *(const float4*)&emb[(r0 + c) * DIM + u * 32 + v * 4];
    }

    const int tm = tid >> 4, tn = tid & 15;
    float acc[4][4] = {};

    for (int cc = 0; cc < 2; ++cc) {
        __syncthreads();                     // A-writes (cc=0) / prev reads done
        {   // stage B chunk [64k x 64col]
            const int u = tid & 15, kk = tid >> 4;
            #pragma unroll
            for (int m = 0; m < 4; ++m) {
                const int k = kk + m * 16;
                *(float4*)&Bs[k * 68 + u * 4] =
                    *(const float4*)&Bsrc[(cc * 64 + k) * HID + cb + u * 4];
            }
        }
        __syncthreads();
        #pragma unroll 2
        for (int k4 = 0; k4 < 16; ++k4) {
            float4 a4[4];
            #pragma unroll
            for (int i = 0; i < 4; ++i)
                a4[i] = *(const float4*)&As[(tm * 4 + i) * 132 + cc * 64 + k4 * 4];
            #pragma unroll
            for (int m = 0; m < 4; ++m) {
                const float4 b4 = *(const float4*)&Bs[(k4 * 4 + m) * 68 + tn * 4];
                #pragma unroll
                for (int i = 0; i < 4; ++i) {
                    const float a = (m == 0) ? a4[i].x : (m == 1) ? a4[i].y
                                  : (m == 2) ? a4[i].z : a4[i].w;
                    acc[i][0] = fmaf(a, b4.x, acc[i][0]);
                    acc[i][1] = fmaf(a, b4.y, acc[i][1]);
                    acc[i][2] = fmaf(a, b4.z, acc[i][2]);
                    acc[i][3] = fmaf(a, b4.w, acc[i][3]);
                }
            }
        }
    }

    if (seg == 0) {
        const float4 ba4 = *(const float4*)&ba1[cb + tn * 4];
        const float4 wa4 = *(const float4*)&wa2[cb + tn * 4];
        #pragma unroll
        for (int i = 0; i < 4; ++i) {
            float s = fmaxf(acc[i][0] + ba4.x, 0.f) * wa4.x
                    + fmaxf(acc[i][1] + ba4.y, 0.f) * wa4.y
                    + fmaxf(acc[i][2] + ba4.z, 0.f) * wa4.z
                    + fmaxf(acc[i][3] + ba4.w, 0.f) * wa4.w;
            s += __shfl_xor(s, 1);
            s += __shfl_xor(s, 2);
            s += __shfl_xor(s, 4);
            s += __shfl_xor(s, 8);
            if (tn == 0)
                score_part[(bn & 3) * M_TOT + r0 + tm * 4 + i] = s;
        }
    } else if (seg == 1) {
        const float4 bd4 = *(const float4*)&bd1[cb + tn * 4];
        #pragma unroll
        for (int i = 0; i < 4; ++i) {
            float4 o = { acc[i][0] + bd4.x, acc[i][1] + bd4.y,
                         acc[i][2] + bd4.z, acc[i][3] + bd4.w };
            *(float4*)&Ai[(r0 + tm * 4 + i) * HID + cb + tn * 4] = o;
        }
    } else {
        #pragma unroll
        for (int i = 0; i < 4; ++i) {
            float4 o = { acc[i][0], acc[i][1], acc[i][2], acc[i][3] };
            *(float4*)&Aj[(r0 + tm * 4 + i) * HID + cb + tn * 4] = o;
        }
    }
}

// ---------------------------------------------------------------------------
// K3: softmax over N=384 per batch; input = 4 score partials summed.
// (ba2 dropped: softmax is shift-invariant.)
// ---------------------------------------------------------------------------
__global__ __launch_bounds__(NCITY) void softmax_kernel(
    const float* __restrict__ score_part, float* __restrict__ att)
{
    __shared__ float red[8];
    const int b = blockIdx.x, t = threadIdx.x;
    const int idx = b * NCITY + t;
    const float v = score_part[idx] + score_part[M_TOT + idx]
                  + score_part[2 * M_TOT + idx] + score_part[3 * M_TOT + idx];

    float m = v;
    #pragma unroll
    for (int off = 32; off > 0; off >>= 1)
        m = fmaxf(m, __shfl_down(m, off));
    if ((t & 63) == 0) red[t >> 6] = m;
    __syncthreads();
    m = red[0];
    #pragma unroll
    for (int w = 1; w < NCITY / 64; ++w) m = fmaxf(m, red[w]);

    const float e = __expf(v - m);
    float s = e;
    #pragma unroll
    for (int off = 32; off > 0; off >>= 1)
        s += __shfl_down(s, off);
    __syncthreads();
    if ((t & 63) == 0) red[t >> 6] = s;
    __syncthreads();
    s = 0.f;
    #pragma unroll
    for (int w = 0; w < NCITY / 64; ++w) s += red[w];

    att[idx] = e / s;
}

// ---------------------------------------------------------------------------
// K4: pairwise decoder (unchanged from R1/R2 — ~3-4 us, near packed-VALU floor).
// ---------------------------------------------------------------------------
__global__ __launch_bounds__(256) void pair_kernel(
    const float* __restrict__ Ai, const float* __restrict__ Aj,
    const float* __restrict__ wd2, const float* __restrict__ bd2,
    float* __restrict__ p)
{
    __shared__ float ai_s[32 * HID];
    __shared__ float aj_s[32 * HID];

    const int tid = threadIdx.x;
    const int b  = blockIdx.z;
    const int i0 = blockIdx.y * 32;
    const int j0 = blockIdx.x * 32;

    for (int t = tid; t < 32 * (HID / 4); t += 256) {
        const int r  = t >> 6;
        const int c4 = t & 63;
        const int cs = (c4 ^ (r & 7)) << 2;
        *(float4*)&ai_s[r * HID + cs] =
            *(const float4*)&Ai[(b * NCITY + i0 + r) * HID + (c4 << 2)];
        *(float4*)&aj_s[r * HID + cs] =
            *(const float4*)&Aj[(b * NCITY + j0 + r) * HID + (c4 << 2)];
    }
    __syncthreads();

    const int tx = tid & 15;
    const int ty = tid >> 4;
    const int sxi = ty & 7;
    const int sxj = tx & 7;

    float acc00 = 0.f, acc01 = 0.f, acc10 = 0.f, acc11 = 0.f;

    #pragma unroll 4
    for (int k4 = 0; k4 < HID / 4; ++k4) {
        const int k  = k4 << 2;
        const int ci = (k4 ^ sxi) << 2;
        const int cj = (k4 ^ sxj) << 2;
        const float4 w  = *(const float4*)&wd2[k];
        const float4 x0 = *(const float4*)&ai_s[ ty       * HID + ci];
        const float4 x1 = *(const float4*)&ai_s[(ty + 16) * HID + ci];
        const float4 y0 = *(const float4*)&aj_s[ tx       * HID + cj];
        const float4 y1 = *(const float4*)&aj_s[(tx + 16) * HID + cj];

#define PK(ACC, X, Y)                                                  \
        ACC = fmaf(fmaxf(X.x + Y.x, 0.f), w.x, ACC);                   \
        ACC = fmaf(fmaxf(X.y + Y.y, 0.f), w.y, ACC);                   \
        ACC = fmaf(fmaxf(X.z + Y.z, 0.f), w.z, ACC);                   \
        ACC = fmaf(fmaxf(X.w + Y.w, 0.f), w.w, ACC);
        PK(acc00, x0, y0)
        PK(acc01, x0, y1)
        PK(acc10, x1, y0)
        PK(acc11, x1, y1)
#undef PK
    }

    const float bd = bd2[0];
    float accs[2][2] = {{acc00, acc01}, {acc10, acc11}};
    #pragma unroll
    for (int ii = 0; ii < 2; ++ii) {
        #pragma unroll
        for (int jj = 0; jj < 2; ++jj) {
            const int gi = i0 + ty + ii * 16;
            const int gj = j0 + tx + jj * 16;
            const float v = 1.f / (1.f + __expf(-(accs[ii][jj] + bd)));
            p[(b * NCITY + gi) * NCITY + gj] = (gi == gj) ? 0.f : v;
        }
    }
}

// ---------------------------------------------------------------------------
extern "C" void kernel_launch(void* const* d_in, const int* in_sizes, int n_in,
                              void* d_out, int out_size, void* d_ws, size_t ws_size,
                              hipStream_t stream)
{
    const float* cities = (const float*)d_in[0];
    const float* We1    = (const float*)d_in[1];
    const float* be1    = (const float*)d_in[2];
    const float* We2    = (const float*)d_in[3];
    const float* be2    = (const float*)d_in[4];
    const float* Wa1    = (const float*)d_in[5];
    const float* ba1    = (const float*)d_in[6];
    const float* wa2    = (const float*)d_in[7];
    const float* ba2    = (const float*)d_in[8];
    const float* Wd1    = (const float*)d_in[9];
    const float* bd1    = (const float*)d_in[10];
    const float* wd2    = (const float*)d_in[11];
    const float* bd2    = (const float*)d_in[12];
    (void)ba2;

    float* out_att = (float*)d_out;                 // [4,384]
    float* out_p   = out_att + BATCH * NCITY;       // [4,384,384]

    float* score_part = (float*)d_ws;               // [4][1536]
    float* emb        = score_part + 4 * M_TOT;     // [1536][128]
    float* Ai         = emb + M_TOT * DIM;          // [1536][256]
    float* Aj         = Ai + M_TOT * HID;           // [1536][256]

    emb_kernel<<<dim3(2, 96), 256, 0, stream>>>(
        cities, We1, be1, We2, be2, emb);

    heads_kernel<<<dim3(12, 24), 256, 0, stream>>>(
        emb, Wa1, ba1, wa2, Wd1, bd1, score_part, Ai, Aj);

    softmax_kernel<<<BATCH, NCITY, 0, stream>>>(score_part, out_att);

    pair_kernel<<<dim3(NCITY / 32, NCITY / 32, BATCH), 256, 0, stream>>>(
        Ai, Aj, wd2, bd2, out_p);
}